// Round 11
// baseline (274.275 us; speedup 1.0000x reference)
//
#include <hip/hip_runtime.h>
#include <math.h>

#define NBINS 28
#define L2E 1.44269504088896340736f

#define EXP2F(x) __builtin_amdgcn_exp2f(x)
#define RCPF(x)  __builtin_amdgcn_rcpf(x)

// R8 lesson: in HIP mode the AMDGPU builtins' half type is __fp16.
typedef __fp16 h2t __attribute__((ext_vector_type(2)));

// fdot2: d = a.x*b.x + a.y*b.y + c  (f16 inputs, f32 accumulate, 1 VALU slot)
static __device__ __forceinline__ float fdot2(h2t a, h2t b, float c) {
    return __builtin_amdgcn_fdot2(a, b, c, false);
}
static __device__ __forceinline__ h2t pkx(float lo, float hi) {
    return __builtin_amdgcn_cvt_pkrtz(lo, hi);   // .x = lo, .y = hi
}
static __device__ __forceinline__ h2t asH2(float f) {
    union { float f; h2t h; } u; u.f = f; return u.h;
}

// workspace float offsets (R9 layout: f32 region + packed-f16 pairs).
#define WS_TBL 0    // 40 floats: ml_table[d-1] = exp(ml_mlp(d) - 0.25 d), d=1..40
#define WS_W1  64   // 128 floats, row-major, * -log2e   (unused by f16 path)
#define WS_B1  192  // 16, * -log2e
#define WS_W2  208  // 256 floats, row-major, * -log2e   (unused by f16 path)
#define WS_B2  464  // 16, * -log2e
#define WS_W3  480  // 16, * +log2e
#define WS_B3  496  // 1, * +log2e
#define WP_W1  512  // 64 dwords:  pack(f16(-L2E*W1[2f2][j]), f16(-L2E*W1[2f2+1][j]))
#define WP_W2  576  // 128 dwords: pack(f16(-L2E*W2[2k2][j]), f16(-L2E*W2[2k2+1][j]))
#define WS_TOT 704

__global__ void prep_kernel(const float* __restrict__ mh_W1, const float* __restrict__ mh_b1,
                            const float* __restrict__ mh_W2, const float* __restrict__ mh_b2,
                            const float* __restrict__ mh_W3, const float* __restrict__ mh_b3,
                            const float* __restrict__ ml_W1, const float* __restrict__ ml_b1,
                            const float* __restrict__ ml_W2, const float* __restrict__ ml_b2,
                            const float* __restrict__ ml_W3, const float* __restrict__ ml_b3,
                            float* __restrict__ ws, float* __restrict__ out_bins) {
    const int t = threadIdx.x;  // 64 threads
    for (int k = t; k < 128; k += 64) ws[WS_W1 + k] = -L2E * mh_W1[k];
    for (int k = t; k < 16;  k += 64) ws[WS_B1 + k] = -L2E * mh_b1[k];
    for (int k = t; k < 256; k += 64) ws[WS_W2 + k] = -L2E * mh_W2[k];
    for (int k = t; k < 16;  k += 64) ws[WS_B2 + k] = -L2E * mh_b2[k];
    for (int k = t; k < 16;  k += 64) ws[WS_W3 + k] =  L2E * mh_W3[k];
    if (t == 0) ws[WS_B3] = L2E * mh_b3[0];

    for (int k = t; k < 64; k += 64) {       // k = f2*16 + j
        const int f2 = k >> 4, j = k & 15;
        union { __fp16 h[2]; float f; } u;
        u.h[0] = (__fp16)(-L2E * mh_W1[(2 * f2)     * 16 + j]);
        u.h[1] = (__fp16)(-L2E * mh_W1[(2 * f2 + 1) * 16 + j]);
        ws[WP_W1 + k] = u.f;
    }
    for (int k = t; k < 128; k += 64) {      // k = k2*16 + j
        const int k2 = k >> 4, j = k & 15;
        union { __fp16 h[2]; float f; } u;
        u.h[0] = (__fp16)(-L2E * mh_W2[(2 * k2)     * 16 + j]);
        u.h[1] = (__fp16)(-L2E * mh_W2[(2 * k2 + 1) * 16 + j]);
        ws[WP_W2 + k] = u.f;
    }

    if (t < 40) {
        const float x = (float)(t + 1);
        float h1[16], h2[16];
        #pragma unroll
        for (int j = 0; j < 16; ++j)
            h1[j] = 1.0f / (1.0f + expf(-(x * ml_W1[j] + ml_b1[j])));
        #pragma unroll
        for (int j = 0; j < 16; ++j) {
            float a = ml_b2[j];
            #pragma unroll
            for (int k = 0; k < 16; ++k) a = fmaf(h1[k], ml_W2[k * 16 + j], a);
            h2[j] = 1.0f / (1.0f + expf(-a));
        }
        float phi = ml_b3[0];
        #pragma unroll
        for (int k = 0; k < 16; ++k) phi = fmaf(h2[k], ml_W3[k], phi);
        const float sc = expf(phi - 0.25f * x);
        ws[WS_TBL + t] = sc;
        if (t < NBINS) out_bins[t] = sc;  // dl2_scores term of output 1
    }
}

// R11 = R10's persistent prefetch pipeline x R6's 4-row-innermost body.
// Mechanism: only ~60 of the 217 uniform weight dwords stay live in
// SGPRs, so the rest are re-loaded from K$ every loop iteration; with
// 4 rows/iteration each reload feeds 4 rows instead of 2 (halving
// per-row weight-wait + loop overhead).  R6 proved the 4-row body is
// clean (56 VGPR); R10 proved the pipeline kills the entry-latency
// floor; this combines them.  Grid: 1024 blocks x 256 thr x 4 iters
// = exactly 1M quads (N=4e6), zero tail.
struct QuadIn {
    float4 x[8];
    int4 dl, ml;
};

__global__ __launch_bounds__(256) void main_kernel(
        const float4* __restrict__ x4,
        const int4* __restrict__ dl4p,
        const int4* __restrict__ ml4p,
        const float* __restrict__ ws,
        float4* __restrict__ out4,
        float* __restrict__ out_bins,
        int nquad, int stride, int iters) {
    __shared__ float s_tbl[40];
    __shared__ float s_bins[4 * NBINS];
    const int tid = threadIdx.x;
    if (tid < 40) s_tbl[tid] = ws[WS_TBL + tid];
    if (tid < 4 * NBINS) s_bins[tid] = 0.0f;
    __syncthreads();

    float* myb = &s_bins[(tid >> 6) * NBINS];

    int q = blockIdx.x * 256 + tid;

    // preload iteration 0
    QuadIn cur;
    {
        const int qc = (q < nquad) ? q : 0;
        #pragma unroll
        for (int i = 0; i < 8; ++i) cur.x[i] = x4[8 * qc + i];
        cur.dl = dl4p[qc];  cur.ml = ml4p[qc];
    }

    #pragma unroll 1
    for (int it = 0; it < iters; ++it) {
        // ---- issue next iteration's loads before current compute ----
        QuadIn nxt;
        const int qn = q + stride;
        if (it + 1 < iters) {
            const int qcn = (qn < nquad) ? qn : 0;
            #pragma unroll
            for (int i = 0; i < 8; ++i) nxt.x[i] = x4[8 * qcn + i];
            nxt.dl = dl4p[qcn];  nxt.ml = ml4p[qcn];
        }

        const bool active = (q < nquad);
        const int dlv[4] = {cur.dl.x, cur.dl.y, cur.dl.z, cur.dl.w};
        const int mlv[4] = {cur.ml.x, cur.ml.y, cur.ml.z, cur.ml.w};

        // pack x to f16 pairs along the feature dim: xp[row][f2]
        h2t xp[4][4];
        #pragma unroll
        for (int r = 0; r < 4; ++r) {
            const float4 a = cur.x[2 * r + 0];
            const float4 b = cur.x[2 * r + 1];
            xp[r][0] = pkx(a.x, a.y); xp[r][1] = pkx(a.z, a.w);
            xp[r][2] = pkx(b.x, b.y); xp[r][3] = pkx(b.z, b.w);
        }

        // ---- layer 1: 8 -> 16 via dot2, rows innermost ----
        float u[4][16];
        #pragma unroll
        for (int j = 0; j < 16; ++j) {
            const float b = ws[WS_B1 + j];
            #pragma unroll
            for (int r = 0; r < 4; ++r) u[r][j] = b;
        }
        #pragma unroll
        for (int f2 = 0; f2 < 4; ++f2) {
            #pragma unroll
            for (int j = 0; j < 16; ++j) {
                const h2t w = asH2(ws[WP_W1 + f2 * 16 + j]);
                #pragma unroll
                for (int r = 0; r < 4; ++r) u[r][j] = fdot2(xp[r][f2], w, u[r][j]);
            }
        }
        // sigmoid in f32, pack h pairs along k: hp[row][k2]
        h2t hp[4][8];
        #pragma unroll
        for (int k2 = 0; k2 < 8; ++k2) {
            #pragma unroll
            for (int r = 0; r < 4; ++r) {
                const float ha = RCPF(1.0f + EXP2F(u[r][2 * k2]));
                const float hb = RCPF(1.0f + EXP2F(u[r][2 * k2 + 1]));
                hp[r][k2] = pkx(ha, hb);
            }
        }

        // ---- layer 2: 16 -> 16 via dot2, rows innermost ----
        float v[4][16];
        #pragma unroll
        for (int j = 0; j < 16; ++j) {
            const float b = ws[WS_B2 + j];
            #pragma unroll
            for (int r = 0; r < 4; ++r) v[r][j] = b;
        }
        #pragma unroll
        for (int k2 = 0; k2 < 8; ++k2) {
            #pragma unroll
            for (int j = 0; j < 16; ++j) {
                const h2t w = asH2(ws[WP_W2 + k2 * 16 + j]);
                #pragma unroll
                for (int r = 0; r < 4; ++r) v[r][j] = fdot2(hp[r][k2], w, v[r][j]);
            }
        }

        // ---- layer 3 + psi (f32) ----
        const float pb = ws[WS_B3];          // prescaled by +log2e
        float phi[4] = {pb, pb, pb, pb};
        #pragma unroll
        for (int j = 0; j < 16; ++j) {
            const float w3 = ws[WS_W3 + j];  // prescaled by +log2e
            #pragma unroll
            for (int r = 0; r < 4; ++r)
                phi[r] = fmaf(RCPF(1.0f + EXP2F(v[r][j])), w3, phi[r]);
        }
        float sc[4];
        #pragma unroll
        for (int r = 0; r < 4; ++r)
            sc[r] = EXP2F(fmaf((float)dlv[r], -0.25f * L2E, phi[r]));

        // ---- epilogue for current quad ----
        if (active) {
            float ov[4];
            #pragma unroll
            for (int r = 0; r < 4; ++r) {
                const int i = min(max(dlv[r], 1), 40) - 1;
                ov[r] = sc[r] + ((dlv[r] == mlv[r]) ? s_tbl[i] : 0.0f);
            }
            float4 o; o.x = ov[0]; o.y = ov[1]; o.z = ov[2]; o.w = ov[3];
            out4[q] = o;
            #pragma unroll
            for (int r = 0; r < 4; ++r)
                if (dlv[r] >= 1 && dlv[r] <= NBINS)
                    unsafeAtomicAdd(&myb[dlv[r] - 1], sc[r]);
        }

        cur = nxt;
        q = qn;
    }

    __syncthreads();
    if (tid < NBINS) {
        const float bsum = s_bins[tid] + s_bins[NBINS + tid] +
                           s_bins[2 * NBINS + tid] + s_bins[3 * NBINS + tid];
        unsafeAtomicAdd(&out_bins[tid], bsum);
    }
}

extern "C" void kernel_launch(void* const* d_in, const int* in_sizes, int n_in,
                              void* d_out, int out_size, void* d_ws, size_t ws_size,
                              hipStream_t stream) {
    const int n = in_sizes[0] / 8;  // N rows (N = 4e6, divisible by 4)

    const float* x_feat = (const float*)d_in[0];
    const float* mh_W1  = (const float*)d_in[1];
    const float* mh_b1  = (const float*)d_in[2];
    const float* mh_W2  = (const float*)d_in[3];
    const float* mh_b2  = (const float*)d_in[4];
    const float* mh_W3  = (const float*)d_in[5];
    const float* mh_b3  = (const float*)d_in[6];
    const float* ml_W1  = (const float*)d_in[7];
    const float* ml_b1  = (const float*)d_in[8];
    const float* ml_W2  = (const float*)d_in[9];
    const float* ml_b2  = (const float*)d_in[10];
    const float* ml_W3  = (const float*)d_in[11];
    const float* ml_b3  = (const float*)d_in[12];
    const int* del_lens = (const int*)d_in[13];
    const int* mh_len   = (const int*)d_in[14];

    float* out      = (float*)d_out;
    float* out_bins = out + n;  // last 28 elements of d_out
    float* ws       = (float*)d_ws;

    prep_kernel<<<dim3(1), dim3(64), 0, stream>>>(
        mh_W1, mh_b1, mh_W2, mh_b2, mh_W3, mh_b3,
        ml_W1, ml_b1, ml_W2, ml_b2, ml_W3, ml_b3,
        ws, out_bins);

    const int nquad = n / 4;
    int nblocks = 1024;                       // persistent grid, 4 blocks/CU
    const int needed = (nquad + 255) / 256;
    if (needed < nblocks) nblocks = needed;
    const int stride = nblocks * 256;
    const int iters = (nquad + stride - 1) / stride;
    main_kernel<<<dim3(nblocks), dim3(256), 0, stream>>>(
        (const float4*)x_feat, (const int4*)del_lens, (const int4*)mh_len,
        ws, (float4*)out, out_bins, nquad, stride, iters);
}